// Round 2
// baseline (4312.609 us; speedup 1.0000x reference)
//
#include <hip/hip_runtime.h>
#include <cstdint>
#include <cstddef>

#define T_TOK 4096
#define H_DIM 2048
#define I_DIM 4096
#define E_NUM 8
#define CAP_ROWS 9216   // max padded rows: 8192 + 8*127 = 9208

// ---------------- workspace layout (bytes) ----------------
#define OFF_COUNTS   0                               // int[8]
#define OFF_CURSOR   64                              // int[8]
#define OFF_PADOFF   128                             // int[9]
#define OFF_TOKIDX   1024                            // int[CAP_ROWS]
#define OFF_TOKGATE  (OFF_TOKIDX + CAP_ROWS*4)       // float[CAP_ROWS]
#define OFF_TOKSLOT  (OFF_TOKGATE + CAP_ROWS*4)      // int[2*T_TOK]
#define OFF_XQ       ((size_t)131072)                            // fp8[CAP][H]
#define OFF_AQ       (OFF_XQ + (size_t)CAP_ROWS*H_DIM)           // fp8[CAP][I]
#define OFF_YB       (OFF_AQ + (size_t)CAP_ROWS*I_DIM)           // f32[CAP][H]
#define OFF_W1Q      (OFF_YB + (size_t)CAP_ROWS*H_DIM*4)         // fp8[E][2I][H]
#define OFF_W2Q      (OFF_W1Q + (size_t)E_NUM*2*I_DIM*H_DIM)     // fp8[E][H][I]

typedef int   i32x4 __attribute__((ext_vector_type(4)));
typedef int   i32x8 __attribute__((ext_vector_type(8)));
typedef float f32x4 __attribute__((ext_vector_type(4)));

// RNE round of f32 to the fp8 e4m3fn grid (after clip to +-448), returned as f32.
__device__ __forceinline__ float fp8_round(float v) {
  v = fminf(448.f, fmaxf(-448.f, v));
  float av = fabsf(v);
  if (av < 0.015625f) {                 // subnormal grid, step 2^-9
    return rintf(v * 512.f) * (1.f / 512.f);
  }
  unsigned u = __float_as_uint(v);
  unsigned lsb = (u >> 20) & 1u;        // RNE to 3 mantissa bits
  u += 0x7FFFFu + lsb;
  u &= 0xFFF00000u;
  return __uint_as_float(u);
}

// exact e4m3fn encode of an on-grid f32 value
__device__ __forceinline__ unsigned fp8_enc(float v) {
  unsigned u = __float_as_uint(v);
  unsigned s = (u >> 24) & 0x80u;
  float av = fabsf(v);
  if (av < 0.015625f) {                 // subnormal: mant = av*512 (exact 0..7)
    unsigned m = (unsigned)(av * 512.0f + 0.5f);
    return s | m;
  }
  unsigned E = (u >> 23) & 0xFFu;       // 121..135
  unsigned mant = (u >> 20) & 7u;
  return s | ((E - 120u) << 3) | mant;
}

__device__ __forceinline__ void gld16(const void* g, void* l) {
  __builtin_amdgcn_global_load_lds(
      (__attribute__((address_space(1))) void*)((void*)g),
      (__attribute__((address_space(3))) void*)l, 16, 0, 0);
}

// swizzled fragment load: tile is 128B-per-row fp8, chunk c stored at slot c^(row&7)
__device__ __forceinline__ i32x8 frag_ld(const unsigned char* tile, int rowIdx, int quad) {
  const int s = rowIdx & 7;
  const unsigned char* r = tile + rowIdx * 128;
  i32x4 lo = *(const i32x4*)(r + (((quad * 2)     ^ s) * 16));
  i32x4 hi = *(const i32x4*)(r + (((quad * 2 + 1) ^ s) * 16));
  return __builtin_shufflevector(lo, hi, 0, 1, 2, 3, 4, 5, 6, 7);
}

// ---------------- routing ----------------
__global__ void k_count(const int* __restrict__ se, int* __restrict__ counts) {
  int t = blockIdx.x * 256 + threadIdx.x;
  if (t >= T_TOK) return;
  int e0 = se[t * 2], e1 = se[t * 2 + 1];
  atomicAdd(&counts[e0], 1);
  if (e1 != e0) atomicAdd(&counts[e1], 1);
}

__global__ void k_offsets(const int* __restrict__ counts, int* __restrict__ padOff) {
  if (threadIdx.x == 0 && blockIdx.x == 0) {
    int acc = 0;
    for (int e = 0; e < E_NUM; e++) {
      padOff[e] = acc;
      acc += ((counts[e] + 127) / 128) * 128;
    }
    padOff[E_NUM] = acc;
  }
}

__global__ void k_fill(const int* __restrict__ se, const float* __restrict__ rw,
                       const int* __restrict__ padOff, int* __restrict__ cursor,
                       int* __restrict__ tokIdx, float* __restrict__ tokGate,
                       int* __restrict__ tokSlot) {
  int t = blockIdx.x * 256 + threadIdx.x;
  if (t >= T_TOK) return;
  int e0 = se[t * 2], e1 = se[t * 2 + 1];
  float w0 = rw[t * 2], w1 = rw[t * 2 + 1];
  float g0 = w0 + (e1 == e0 ? w1 : 0.f);
  int s0 = atomicAdd(&cursor[e0], 1);
  int r0 = padOff[e0] + s0;
  tokIdx[r0] = t; tokGate[r0] = g0; tokSlot[t * 2] = r0;
  if (e1 != e0) {
    int s1 = atomicAdd(&cursor[e1], 1);
    int r1 = padOff[e1] + s1;
    tokIdx[r1] = t; tokGate[r1] = w1; tokSlot[t * 2 + 1] = r1;
  } else {
    tokSlot[t * 2 + 1] = -1;
  }
}

// ---------------- gather + quantize x -> fp8 bytes ----------------
__global__ __launch_bounds__(256)
void k_gather(const float* __restrict__ x, const int* __restrict__ padOff,
              const int* __restrict__ counts, const int* __restrict__ tokIdx,
              const float* __restrict__ w1_is, unsigned char* __restrict__ xq) {
  const int rblk = blockIdx.x;
  if (rblk >= padOff[E_NUM]) return;
  int e = 0;
  while (rblk >= padOff[e + 1]) e++;
  unsigned char* dst = xq + (size_t)rblk * H_DIM + threadIdx.x * 8;
  const int local = rblk - padOff[e];
  if (local >= counts[e]) {
    *(uint2*)dst = make_uint2(0u, 0u);
    return;
  }
  const int tok = tokIdx[rblk];
  const float is = w1_is[e];
  const float* src = x + (size_t)tok * H_DIM + threadIdx.x * 8;
  float4 v0 = *(const float4*)(src);
  float4 v1 = *(const float4*)(src + 4);
  unsigned lo = fp8_enc(fp8_round(v0.x / is)) | (fp8_enc(fp8_round(v0.y / is)) << 8) |
                (fp8_enc(fp8_round(v0.z / is)) << 16) | (fp8_enc(fp8_round(v0.w / is)) << 24);
  unsigned hi = fp8_enc(fp8_round(v1.x / is)) | (fp8_enc(fp8_round(v1.y / is)) << 8) |
                (fp8_enc(fp8_round(v1.z / is)) << 16) | (fp8_enc(fp8_round(v1.w / is)) << 24);
  *(uint2*)dst = make_uint2(lo, hi);
}

// ---------------- weight convert f32 -> fp8 bytes (exact, on-grid input) -------
__global__ __launch_bounds__(256)
void k_wconv(const float* __restrict__ w, unsigned char* __restrict__ o, long n8) {
  long i = (long)blockIdx.x * 256 + threadIdx.x;
  if (i >= n8) return;
  float4 v0 = ((const float4*)w)[i * 2];
  float4 v1 = ((const float4*)w)[i * 2 + 1];
  unsigned lo = fp8_enc(v0.x) | (fp8_enc(v0.y) << 8) | (fp8_enc(v0.z) << 16) | (fp8_enc(v0.w) << 24);
  unsigned hi = fp8_enc(v1.x) | (fp8_enc(v1.y) << 8) | (fp8_enc(v1.z) << 16) | (fp8_enc(v1.w) << 24);
  ((uint2*)o)[i] = make_uint2(lo, hi);
}

// ---------------- GEMM1: MX fp8, tile 128m x (64 g-cols + 64 u-cols), BK=128 ---
// grid: (I/64, 32, E); block 512 = 8 waves; wave tile 32m x 32n, dual g/u acc
__global__ __launch_bounds__(512, 4)
void k_gemm1(const unsigned char* __restrict__ xq,
             const unsigned char* __restrict__ w1q,
             const int* __restrict__ padOff,
             const float* __restrict__ w1_is, const float* __restrict__ w1_ws,
             const float* __restrict__ w2_is,
             unsigned char* __restrict__ aq) {
  const int e = blockIdx.z;
  const int rbase = padOff[e];
  const int rows = padOff[e + 1] - rbase;
  const int mt = blockIdx.y;
  if (mt * 128 >= rows) return;
  const int nt = blockIdx.x;

  __shared__ __align__(16) unsigned char As[128 * 128];
  __shared__ __align__(16) unsigned char Bg[64 * 128];
  __shared__ __align__(16) unsigned char Bu[64 * 128];

  const int tid = threadIdx.x;
  const int lane = tid & 63;
  const int wave = tid >> 6;
  const int wm = wave >> 1, wn = wave & 1;
  const int lr = lane & 15, quad = lane >> 4;

  // staging: slot p -> row p>>3, phys chunk p&7, logical chunk (p&7)^(row&7)
  const int pr0 = tid >> 3,          pc0 = (tid & 7) ^ (pr0 & 7);
  const int pr1 = (512 + tid) >> 3,  pc1 = ((512 + tid) & 7) ^ (pr1 & 7);
  const unsigned char* gA0 = xq + (size_t)(rbase + mt * 128 + pr0) * H_DIM + pc0 * 16;
  const unsigned char* gA1 = xq + (size_t)(rbase + mt * 128 + pr1) * H_DIM + pc1 * 16;
  const unsigned char* gBg = w1q + ((size_t)e * 2 * I_DIM + nt * 64 + pr0) * H_DIM + pc0 * 16;
  const unsigned char* gBu = w1q + ((size_t)e * 2 * I_DIM + I_DIM + nt * 64 + pr0) * H_DIM + pc0 * 16;
  unsigned char* lA0 = As + tid * 16;
  unsigned char* lA1 = As + (512 + tid) * 16;
  unsigned char* lBg = Bg + tid * 16;
  unsigned char* lBu = Bu + tid * 16;

  f32x4 accg[2][2] = {};
  f32x4 accu[2][2] = {};

  for (int k0 = 0; k0 < H_DIM; k0 += 128) {
    gld16(gA0 + k0, lA0);
    gld16(gA1 + k0, lA1);
    gld16(gBg + k0, lBg);
    gld16(gBu + k0, lBu);
    __syncthreads();
    i32x8 af[2], gf[2], uf[2];
#pragma unroll
    for (int i = 0; i < 2; i++)
      af[i] = frag_ld(As, wm * 32 + i * 16 + lr, quad);
#pragma unroll
    for (int j = 0; j < 2; j++) {
      gf[j] = frag_ld(Bg, wn * 32 + j * 16 + lr, quad);
      uf[j] = frag_ld(Bu, wn * 32 + j * 16 + lr, quad);
    }
#pragma unroll
    for (int i = 0; i < 2; i++)
#pragma unroll
      for (int j = 0; j < 2; j++) {
        accg[i][j] = __builtin_amdgcn_mfma_scale_f32_16x16x128_f8f6f4(
            af[i], gf[j], accg[i][j], 0, 0, 0, 127, 0, 127);
        accu[i][j] = __builtin_amdgcn_mfma_scale_f32_16x16x128_f8f6f4(
            af[i], uf[j], accu[i][j], 0, 0, 0, 127, 0, 127);
      }
    __syncthreads();
  }

  const float s1 = w1_is[e] * w1_ws[e];
  const float is2 = w2_is[e];
#pragma unroll
  for (int i = 0; i < 2; i++)
#pragma unroll
    for (int j = 0; j < 2; j++)
#pragma unroll
      for (int rr = 0; rr < 4; rr++) {
        const int row = wm * 32 + i * 16 + quad * 4 + rr;
        const int col = nt * 64 + wn * 32 + j * 16 + lr;
        float g = accg[i][j][rr] * s1;
        float u = accu[i][j][rr] * s1;
        float a = (g / (1.f + expf(-g))) * u;   // silu(g)*u
        aq[(size_t)(rbase + mt * 128 + row) * I_DIM + col] =
            (unsigned char)fp8_enc(fp8_round(a / is2));
      }
}

// ---------------- GEMM2: MX fp8, tile 128x128, BK=128, write gate-scaled y ----
// grid: (H/128, 32, E); block 512 = 8 waves; wave tile 64m x 32n
__global__ __launch_bounds__(512, 4)
void k_gemm2(const unsigned char* __restrict__ aq,
             const unsigned char* __restrict__ w2q,
             const int* __restrict__ padOff, const int* __restrict__ counts,
             const float* __restrict__ tokGate,
             const float* __restrict__ w2_is, const float* __restrict__ w2_ws,
             float* __restrict__ yb) {
  const int e = blockIdx.z;
  const int rbase = padOff[e];
  const int rows = padOff[e + 1] - rbase;
  const int mt = blockIdx.y;
  if (mt * 128 >= rows) return;
  const int nt = blockIdx.x;
  const int cnt = counts[e];

  __shared__ __align__(16) unsigned char As[128 * 128];
  __shared__ __align__(16) unsigned char Bs[128 * 128];
  __shared__ float sGate[128];

  const int tid = threadIdx.x;
  const int lane = tid & 63;
  const int wave = tid >> 6;
  const int wm = wave >> 2, wn = wave & 3;
  const int lr = lane & 15, quad = lane >> 4;

  if (tid < 128) {
    int rr = mt * 128 + tid;
    sGate[tid] = (rr < cnt) ? tokGate[rbase + rr] : 0.f;
  }

  const int pr0 = tid >> 3,          pc0 = (tid & 7) ^ (pr0 & 7);
  const int pr1 = (512 + tid) >> 3,  pc1 = ((512 + tid) & 7) ^ (pr1 & 7);
  const unsigned char* gA0 = aq + (size_t)(rbase + mt * 128 + pr0) * I_DIM + pc0 * 16;
  const unsigned char* gA1 = aq + (size_t)(rbase + mt * 128 + pr1) * I_DIM + pc1 * 16;
  const unsigned char* gB0 = w2q + ((size_t)e * H_DIM + nt * 128 + pr0) * I_DIM + pc0 * 16;
  const unsigned char* gB1 = w2q + ((size_t)e * H_DIM + nt * 128 + pr1) * I_DIM + pc1 * 16;
  unsigned char* lA0 = As + tid * 16;
  unsigned char* lA1 = As + (512 + tid) * 16;
  unsigned char* lB0 = Bs + tid * 16;
  unsigned char* lB1 = Bs + (512 + tid) * 16;

  f32x4 acc[4][2] = {};

  for (int k0 = 0; k0 < I_DIM; k0 += 128) {
    gld16(gA0 + k0, lA0);
    gld16(gA1 + k0, lA1);
    gld16(gB0 + k0, lB0);
    gld16(gB1 + k0, lB1);
    __syncthreads();
    i32x8 af[4], bf[2];
#pragma unroll
    for (int i = 0; i < 4; i++)
      af[i] = frag_ld(As, wm * 64 + i * 16 + lr, quad);
#pragma unroll
    for (int j = 0; j < 2; j++)
      bf[j] = frag_ld(Bs, wn * 32 + j * 16 + lr, quad);
#pragma unroll
    for (int i = 0; i < 4; i++)
#pragma unroll
      for (int j = 0; j < 2; j++)
        acc[i][j] = __builtin_amdgcn_mfma_scale_f32_16x16x128_f8f6f4(
            af[i], bf[j], acc[i][j], 0, 0, 0, 127, 0, 127);
    __syncthreads();
  }

  const float s2 = w2_is[e] * w2_ws[e];
#pragma unroll
  for (int i = 0; i < 4; i++)
#pragma unroll
    for (int j = 0; j < 2; j++)
#pragma unroll
      for (int rr = 0; rr < 4; rr++) {
        const int row = wm * 64 + i * 16 + quad * 4 + rr;
        const int col = nt * 128 + wn * 32 + j * 16 + lr;
        yb[(size_t)(rbase + mt * 128 + row) * H_DIM + col] =
            acc[i][j][rr] * s2 * sGate[row];
      }
}

// ---------------- combine: out[t] = sum of token's <=2 gate-scaled y rows -----
__global__ __launch_bounds__(256)
void k_combine(const float* __restrict__ yb, const int* __restrict__ tokSlot,
               float* __restrict__ out) {
  int idx = blockIdx.x * 256 + threadIdx.x;     // T*H/4 elements of float4
  int t = idx >> 9;                             // H/4 = 512 float4 per token
  int c = (idx & 511) * 4;
  int s0 = tokSlot[t * 2], s1 = tokSlot[t * 2 + 1];
  float4 v = *(const float4*)(yb + (size_t)s0 * H_DIM + c);
  if (s1 >= 0) {
    float4 w = *(const float4*)(yb + (size_t)s1 * H_DIM + c);
    v.x += w.x; v.y += w.y; v.z += w.z; v.w += w.w;
  }
  *(float4*)(out + (size_t)t * H_DIM + c) = v;
}

// ---------------- host launch ----------------
extern "C" void kernel_launch(void* const* d_in, const int* in_sizes, int n_in,
                              void* d_out, int out_size, void* d_ws, size_t ws_size,
                              hipStream_t stream) {
  const float* x     = (const float*)d_in[0];
  const int*   se    = (const int*)d_in[1];
  const float* rw    = (const float*)d_in[2];
  const float* w1    = (const float*)d_in[3];
  const float* w2    = (const float*)d_in[4];
  const float* w1_is = (const float*)d_in[5];
  const float* w2_is = (const float*)d_in[6];
  const float* w1_ws = (const float*)d_in[7];
  const float* w2_ws = (const float*)d_in[8];
  float* out = (float*)d_out;
  char* ws = (char*)d_ws;

  int*   counts  = (int*)(ws + OFF_COUNTS);
  int*   cursor  = (int*)(ws + OFF_CURSOR);
  int*   padOff  = (int*)(ws + OFF_PADOFF);
  int*   tokIdx  = (int*)(ws + OFF_TOKIDX);
  float* tokGate = (float*)(ws + OFF_TOKGATE);
  int*   tokSlot = (int*)(ws + OFF_TOKSLOT);
  unsigned char* xq  = (unsigned char*)(ws + OFF_XQ);
  unsigned char* aq  = (unsigned char*)(ws + OFF_AQ);
  float*         yb  = (float*)(ws + OFF_YB);
  unsigned char* w1q = (unsigned char*)(ws + OFF_W1Q);
  unsigned char* w2q = (unsigned char*)(ws + OFF_W2Q);

  hipMemsetAsync(ws, 0, 1024, stream);

  k_count  <<<16, 256, 0, stream>>>(se, counts);
  k_offsets<<<1, 1, 0, stream>>>(counts, padOff);
  k_fill   <<<16, 256, 0, stream>>>(se, rw, padOff, cursor, tokIdx, tokGate, tokSlot);
  k_gather <<<CAP_ROWS, 256, 0, stream>>>(x, padOff, counts, tokIdx, w1_is, xq);

  k_wconv<<<65536, 256, 0, stream>>>(w1, w1q, (long)E_NUM * 2 * I_DIM * H_DIM / 8);
  k_wconv<<<32768, 256, 0, stream>>>(w2, w2q, (long)E_NUM * H_DIM * I_DIM / 8);

  dim3 g1(I_DIM / 64, 32, E_NUM);
  k_gemm1<<<g1, 512, 0, stream>>>(xq, w1q, padOff, w1_is, w1_ws, w2_is, aq);

  dim3 g2(H_DIM / 128, 32, E_NUM);
  k_gemm2<<<g2, 512, 0, stream>>>(aq, w2q, padOff, counts, tokGate, w2_is, w2_ws, yb);

  k_combine<<<(T_TOK * H_DIM / 4) / 256, 256, 0, stream>>>(yb, tokSlot, out);
}

// Round 3
// 2676.690 us; speedup vs baseline: 1.6112x; 1.6112x over previous
//
#include <hip/hip_runtime.h>
#include <cstdint>
#include <cstddef>

#define T_TOK 4096
#define H_DIM 2048
#define I_DIM 4096
#define E_NUM 8
#define CAP_ROWS 9216   // max padded rows: 8192 + 8*127 = 9208

// ---------------- workspace layout (bytes) ----------------
#define OFF_COUNTS   0                               // int[8]
#define OFF_CURSOR   64                              // int[8]
#define OFF_PADOFF   128                             // int[9]
#define OFF_TOKIDX   1024                            // int[CAP_ROWS]
#define OFF_TOKGATE  (OFF_TOKIDX + CAP_ROWS*4)       // float[CAP_ROWS]
#define OFF_TOKSLOT  (OFF_TOKGATE + CAP_ROWS*4)      // int[2*T_TOK]
#define OFF_XQ       ((size_t)131072)                            // fp8[CAP][H]
#define OFF_AQ       (OFF_XQ + (size_t)CAP_ROWS*H_DIM)           // fp8[CAP][I]
#define OFF_YB       (OFF_AQ + (size_t)CAP_ROWS*I_DIM)           // f32[CAP][H]
#define OFF_W1Q      (OFF_YB + (size_t)CAP_ROWS*H_DIM*4)         // fp8[E][2I][H]
#define OFF_W2Q      (OFF_W1Q + (size_t)E_NUM*2*I_DIM*H_DIM)     // fp8[E][H][I]

typedef int   i32x4 __attribute__((ext_vector_type(4)));
typedef int   i32x8 __attribute__((ext_vector_type(8)));
typedef float f32x4 __attribute__((ext_vector_type(4)));

// RNE round of f32 to the fp8 e4m3fn grid (after clip to +-448), returned as f32.
__device__ __forceinline__ float fp8_round(float v) {
  v = fminf(448.f, fmaxf(-448.f, v));
  float av = fabsf(v);
  if (av < 0.015625f) {                 // subnormal grid, step 2^-9
    return rintf(v * 512.f) * (1.f / 512.f);
  }
  unsigned u = __float_as_uint(v);
  unsigned lsb = (u >> 20) & 1u;        // RNE to 3 mantissa bits
  u += 0x7FFFFu + lsb;
  u &= 0xFFF00000u;
  return __uint_as_float(u);
}

// exact e4m3fn encode of an on-grid f32 value
__device__ __forceinline__ unsigned fp8_enc(float v) {
  unsigned u = __float_as_uint(v);
  unsigned s = (u >> 24) & 0x80u;
  float av = fabsf(v);
  if (av < 0.015625f) {                 // subnormal: mant = av*512 (exact 0..7)
    unsigned m = (unsigned)(av * 512.0f + 0.5f);
    return s | m;
  }
  unsigned E = (u >> 23) & 0xFFu;       // 121..135
  unsigned mant = (u >> 20) & 7u;
  return s | ((E - 120u) << 3) | mant;
}

__device__ __forceinline__ void gld16(const void* g, void* l) {
  __builtin_amdgcn_global_load_lds(
      (__attribute__((address_space(1))) void*)((void*)g),
      (__attribute__((address_space(3))) void*)l, 16, 0, 0);
}

// swizzled fragment load: tile has 128B rows; logical chunk c lives at slot c^(row&7)
__device__ __forceinline__ i32x8 frag_ld(const unsigned char* tile, int rowIdx, int quad) {
  const int s = rowIdx & 7;
  const unsigned char* r = tile + rowIdx * 128;
  i32x4 lo = *(const i32x4*)(r + (((quad * 2)     ^ s) * 16));
  i32x4 hi = *(const i32x4*)(r + (((quad * 2 + 1) ^ s) * 16));
  return __builtin_shufflevector(lo, hi, 0, 1, 2, 3, 4, 5, 6, 7);
}

// ---------------- routing ----------------
__global__ void k_count(const int* __restrict__ se, int* __restrict__ counts) {
  int t = blockIdx.x * 256 + threadIdx.x;
  if (t >= T_TOK) return;
  int e0 = se[t * 2], e1 = se[t * 2 + 1];
  atomicAdd(&counts[e0], 1);
  if (e1 != e0) atomicAdd(&counts[e1], 1);
}

__global__ void k_offsets(const int* __restrict__ counts, int* __restrict__ padOff) {
  if (threadIdx.x == 0 && blockIdx.x == 0) {
    int acc = 0;
    for (int e = 0; e < E_NUM; e++) {
      padOff[e] = acc;
      acc += ((counts[e] + 127) / 128) * 128;
    }
    padOff[E_NUM] = acc;
  }
}

__global__ void k_fill(const int* __restrict__ se, const float* __restrict__ rw,
                       const int* __restrict__ padOff, int* __restrict__ cursor,
                       int* __restrict__ tokIdx, float* __restrict__ tokGate,
                       int* __restrict__ tokSlot) {
  int t = blockIdx.x * 256 + threadIdx.x;
  if (t >= T_TOK) return;
  int e0 = se[t * 2], e1 = se[t * 2 + 1];
  float w0 = rw[t * 2], w1 = rw[t * 2 + 1];
  float g0 = w0 + (e1 == e0 ? w1 : 0.f);
  int s0 = atomicAdd(&cursor[e0], 1);
  int r0 = padOff[e0] + s0;
  tokIdx[r0] = t; tokGate[r0] = g0; tokSlot[t * 2] = r0;
  if (e1 != e0) {
    int s1 = atomicAdd(&cursor[e1], 1);
    int r1 = padOff[e1] + s1;
    tokIdx[r1] = t; tokGate[r1] = w1; tokSlot[t * 2 + 1] = r1;
  } else {
    tokSlot[t * 2 + 1] = -1;
  }
}

// ---------------- gather + quantize x -> fp8 bytes ----------------
__global__ __launch_bounds__(256)
void k_gather(const float* __restrict__ x, const int* __restrict__ padOff,
              const int* __restrict__ counts, const int* __restrict__ tokIdx,
              const float* __restrict__ w1_is, unsigned char* __restrict__ xq) {
  const int rblk = blockIdx.x;
  if (rblk >= padOff[E_NUM]) return;
  int e = 0;
  while (rblk >= padOff[e + 1]) e++;
  unsigned char* dst = xq + (size_t)rblk * H_DIM + threadIdx.x * 8;
  const int local = rblk - padOff[e];
  if (local >= counts[e]) {
    *(uint2*)dst = make_uint2(0u, 0u);
    return;
  }
  const int tok = tokIdx[rblk];
  const float is = w1_is[e];
  const float* src = x + (size_t)tok * H_DIM + threadIdx.x * 8;
  float4 v0 = *(const float4*)(src);
  float4 v1 = *(const float4*)(src + 4);
  unsigned lo = fp8_enc(fp8_round(v0.x / is)) | (fp8_enc(fp8_round(v0.y / is)) << 8) |
                (fp8_enc(fp8_round(v0.z / is)) << 16) | (fp8_enc(fp8_round(v0.w / is)) << 24);
  unsigned hi = fp8_enc(fp8_round(v1.x / is)) | (fp8_enc(fp8_round(v1.y / is)) << 8) |
                (fp8_enc(fp8_round(v1.z / is)) << 16) | (fp8_enc(fp8_round(v1.w / is)) << 24);
  *(uint2*)dst = make_uint2(lo, hi);
}

// ---------------- weight convert f32 -> fp8 bytes (exact, on-grid input) -------
__global__ __launch_bounds__(256)
void k_wconv(const float* __restrict__ w, unsigned char* __restrict__ o, long n8) {
  long i = (long)blockIdx.x * 256 + threadIdx.x;
  if (i >= n8) return;
  float4 v0 = ((const float4*)w)[i * 2];
  float4 v1 = ((const float4*)w)[i * 2 + 1];
  unsigned lo = fp8_enc(v0.x) | (fp8_enc(v0.y) << 8) | (fp8_enc(v0.z) << 16) | (fp8_enc(v0.w) << 24);
  unsigned hi = fp8_enc(v1.x) | (fp8_enc(v1.y) << 8) | (fp8_enc(v1.z) << 16) | (fp8_enc(v1.w) << 24);
  ((uint2*)o)[i] = make_uint2(lo, hi);
}

// ---------------- GEMM1: MX fp8, tile 128m x 64n of BOTH g and u, BK=128 ------
// grid: (I/64, 32, E); block 256 = 4 waves (2x2); wave tile 64m x 32n, dual acc
__global__ __launch_bounds__(256, 1)
void k_gemm1(const unsigned char* __restrict__ xq,
             const unsigned char* __restrict__ w1q,
             const int* __restrict__ padOff,
             const float* __restrict__ w1_is, const float* __restrict__ w1_ws,
             const float* __restrict__ w2_is,
             unsigned char* __restrict__ aq) {
  const int e = blockIdx.z;
  const int rbase = padOff[e];
  const int rows = padOff[e + 1] - rbase;
  const int mt = blockIdx.y;
  if (mt * 128 >= rows) return;
  const int nt = blockIdx.x;

  __shared__ __align__(16) unsigned char As[128 * 128];
  __shared__ __align__(16) unsigned char Bg[64 * 128];
  __shared__ __align__(16) unsigned char Bu[64 * 128];

  const int tid = threadIdx.x;
  const int lane = tid & 63;
  const int wave = tid >> 6;
  const int wm = wave >> 1, wn = wave & 1;
  const int lr = lane & 15, quad = lane >> 4;

  // staging: slot p -> row p>>3, phys chunk p&7, logical chunk (p&7)^(row&7)
  const unsigned char* gA[4]; unsigned char* lA[4];
#pragma unroll
  for (int s = 0; s < 4; s++) {
    int p = tid + 256 * s, r = p >> 3, c = (p & 7) ^ (r & 7);
    gA[s] = xq + (size_t)(rbase + mt * 128 + r) * H_DIM + c * 16;
    lA[s] = As + p * 16;
  }
  const unsigned char* gG[2]; unsigned char* lG[2];
  const unsigned char* gU[2]; unsigned char* lU[2];
#pragma unroll
  for (int s = 0; s < 2; s++) {
    int p = tid + 256 * s, r = p >> 3, c = (p & 7) ^ (r & 7);
    gG[s] = w1q + ((size_t)e * 2 * I_DIM + nt * 64 + r) * H_DIM + c * 16;
    gU[s] = w1q + ((size_t)e * 2 * I_DIM + I_DIM + nt * 64 + r) * H_DIM + c * 16;
    lG[s] = Bg + p * 16;
    lU[s] = Bu + p * 16;
  }

  f32x4 accg[4][2] = {};
  f32x4 accu[4][2] = {};

  for (int k0 = 0; k0 < H_DIM; k0 += 128) {
#pragma unroll
    for (int s = 0; s < 4; s++) gld16(gA[s] + k0, lA[s]);
#pragma unroll
    for (int s = 0; s < 2; s++) { gld16(gG[s] + k0, lG[s]); gld16(gU[s] + k0, lU[s]); }
    __syncthreads();
    i32x8 gf[2], uf[2];
#pragma unroll
    for (int j = 0; j < 2; j++) {
      gf[j] = frag_ld(Bg, wn * 32 + j * 16 + lr, quad);
      uf[j] = frag_ld(Bu, wn * 32 + j * 16 + lr, quad);
    }
#pragma unroll
    for (int i = 0; i < 4; i++) {
      i32x8 a = frag_ld(As, wm * 64 + i * 16 + lr, quad);
#pragma unroll
      for (int j = 0; j < 2; j++) {
        accg[i][j] = __builtin_amdgcn_mfma_scale_f32_16x16x128_f8f6f4(
            a, gf[j], accg[i][j], 0, 0, 0, 127, 0, 127);
        accu[i][j] = __builtin_amdgcn_mfma_scale_f32_16x16x128_f8f6f4(
            a, uf[j], accu[i][j], 0, 0, 0, 127, 0, 127);
      }
    }
    __syncthreads();
  }

  const float s1 = w1_is[e] * w1_ws[e];
  const float is2 = w2_is[e];
#pragma unroll
  for (int i = 0; i < 4; i++)
#pragma unroll
    for (int j = 0; j < 2; j++)
#pragma unroll
      for (int rr = 0; rr < 4; rr++) {
        const int row = wm * 64 + i * 16 + quad * 4 + rr;
        const int col = nt * 64 + wn * 32 + j * 16 + lr;
        float g = accg[i][j][rr] * s1;
        float u = accu[i][j][rr] * s1;
        float a = (g / (1.f + expf(-g))) * u;   // silu(g)*u
        aq[(size_t)(rbase + mt * 128 + row) * I_DIM + col] =
            (unsigned char)fp8_enc(fp8_round(a / is2));
      }
}

// ---------------- GEMM2: MX fp8, tile 128x128, BK=128, write gate-scaled y ----
// grid: (H/128, 32, E); block 256 = 4 waves (2x2); wave tile 64m x 64n
__global__ __launch_bounds__(256, 1)
void k_gemm2(const unsigned char* __restrict__ aq,
             const unsigned char* __restrict__ w2q,
             const int* __restrict__ padOff, const int* __restrict__ counts,
             const float* __restrict__ tokGate,
             const float* __restrict__ w2_is, const float* __restrict__ w2_ws,
             float* __restrict__ yb) {
  const int e = blockIdx.z;
  const int rbase = padOff[e];
  const int rows = padOff[e + 1] - rbase;
  const int mt = blockIdx.y;
  if (mt * 128 >= rows) return;
  const int nt = blockIdx.x;
  const int cnt = counts[e];

  __shared__ __align__(16) unsigned char As[128 * 128];
  __shared__ __align__(16) unsigned char Bs[128 * 128];
  __shared__ float sGate[128];

  const int tid = threadIdx.x;
  const int lane = tid & 63;
  const int wave = tid >> 6;
  const int wm = wave >> 1, wn = wave & 1;
  const int lr = lane & 15, quad = lane >> 4;

  if (tid < 128) {
    int rr = mt * 128 + tid;
    sGate[tid] = (rr < cnt) ? tokGate[rbase + rr] : 0.f;
  }

  const unsigned char* gA[4]; unsigned char* lA[4];
  const unsigned char* gB[4]; unsigned char* lB[4];
#pragma unroll
  for (int s = 0; s < 4; s++) {
    int p = tid + 256 * s, r = p >> 3, c = (p & 7) ^ (r & 7);
    gA[s] = aq + (size_t)(rbase + mt * 128 + r) * I_DIM + c * 16;
    gB[s] = w2q + ((size_t)e * H_DIM + nt * 128 + r) * I_DIM + c * 16;
    lA[s] = As + p * 16;
    lB[s] = Bs + p * 16;
  }

  f32x4 acc[4][4] = {};

  for (int k0 = 0; k0 < I_DIM; k0 += 128) {
#pragma unroll
    for (int s = 0; s < 4; s++) { gld16(gA[s] + k0, lA[s]); gld16(gB[s] + k0, lB[s]); }
    __syncthreads();
    i32x8 bf[4];
#pragma unroll
    for (int j = 0; j < 4; j++)
      bf[j] = frag_ld(Bs, wn * 64 + j * 16 + lr, quad);
#pragma unroll
    for (int i = 0; i < 4; i++) {
      i32x8 a = frag_ld(As, wm * 64 + i * 16 + lr, quad);
#pragma unroll
      for (int j = 0; j < 4; j++)
        acc[i][j] = __builtin_amdgcn_mfma_scale_f32_16x16x128_f8f6f4(
            a, bf[j], acc[i][j], 0, 0, 0, 127, 0, 127);
    }
    __syncthreads();
  }

  const float s2 = w2_is[e] * w2_ws[e];
#pragma unroll
  for (int i = 0; i < 4; i++)
#pragma unroll
    for (int j = 0; j < 4; j++)
#pragma unroll
      for (int rr = 0; rr < 4; rr++) {
        const int row = wm * 64 + i * 16 + quad * 4 + rr;
        const int col = nt * 128 + wn * 64 + j * 16 + lr;
        yb[(size_t)(rbase + mt * 128 + row) * H_DIM + col] =
            acc[i][j][rr] * s2 * sGate[row];
      }
}

// ---------------- combine: out[t] = sum of token's <=2 gate-scaled y rows -----
__global__ __launch_bounds__(256)
void k_combine(const float* __restrict__ yb, const int* __restrict__ tokSlot,
               float* __restrict__ out) {
  int idx = blockIdx.x * 256 + threadIdx.x;     // T*H/4 elements of float4
  int t = idx >> 9;                             // H/4 = 512 float4 per token
  int c = (idx & 511) * 4;
  int s0 = tokSlot[t * 2], s1 = tokSlot[t * 2 + 1];
  float4 v = *(const float4*)(yb + (size_t)s0 * H_DIM + c);
  if (s1 >= 0) {
    float4 w = *(const float4*)(yb + (size_t)s1 * H_DIM + c);
    v.x += w.x; v.y += w.y; v.z += w.z; v.w += w.w;
  }
  *(float4*)(out + (size_t)t * H_DIM + c) = v;
}

// ---------------- host launch ----------------
extern "C" void kernel_launch(void* const* d_in, const int* in_sizes, int n_in,
                              void* d_out, int out_size, void* d_ws, size_t ws_size,
                              hipStream_t stream) {
  const float* x     = (const float*)d_in[0];
  const int*   se    = (const int*)d_in[1];
  const float* rw    = (const float*)d_in[2];
  const float* w1    = (const float*)d_in[3];
  const float* w2    = (const float*)d_in[4];
  const float* w1_is = (const float*)d_in[5];
  const float* w2_is = (const float*)d_in[6];
  const float* w1_ws = (const float*)d_in[7];
  const float* w2_ws = (const float*)d_in[8];
  float* out = (float*)d_out;
  char* ws = (char*)d_ws;

  int*   counts  = (int*)(ws + OFF_COUNTS);
  int*   cursor  = (int*)(ws + OFF_CURSOR);
  int*   padOff  = (int*)(ws + OFF_PADOFF);
  int*   tokIdx  = (int*)(ws + OFF_TOKIDX);
  float* tokGate = (float*)(ws + OFF_TOKGATE);
  int*   tokSlot = (int*)(ws + OFF_TOKSLOT);
  unsigned char* xq  = (unsigned char*)(ws + OFF_XQ);
  unsigned char* aq  = (unsigned char*)(ws + OFF_AQ);
  float*         yb  = (float*)(ws + OFF_YB);
  unsigned char* w1q = (unsigned char*)(ws + OFF_W1Q);
  unsigned char* w2q = (unsigned char*)(ws + OFF_W2Q);

  hipMemsetAsync(ws, 0, 1024, stream);

  k_count  <<<16, 256, 0, stream>>>(se, counts);
  k_offsets<<<1, 1, 0, stream>>>(counts, padOff);
  k_fill   <<<16, 256, 0, stream>>>(se, rw, padOff, cursor, tokIdx, tokGate, tokSlot);
  k_gather <<<CAP_ROWS, 256, 0, stream>>>(x, padOff, counts, tokIdx, w1_is, xq);

  k_wconv<<<65536, 256, 0, stream>>>(w1, w1q, (long)E_NUM * 2 * I_DIM * H_DIM / 8);
  k_wconv<<<32768, 256, 0, stream>>>(w2, w2q, (long)E_NUM * H_DIM * I_DIM / 8);

  dim3 g1(I_DIM / 64, 32, E_NUM);
  k_gemm1<<<g1, 256, 0, stream>>>(xq, w1q, padOff, w1_is, w1_ws, w2_is, aq);

  dim3 g2(H_DIM / 128, 32, E_NUM);
  k_gemm2<<<g2, 256, 0, stream>>>(aq, w2q, padOff, counts, tokGate, w2_is, w2_ws, yb);

  k_combine<<<(T_TOK * H_DIM / 4) / 256, 256, 0, stream>>>(yb, tokSlot, out);
}